// Round 15
// baseline (10306.107 us; speedup 1.0000x reference)
//
#include <hip/hip_runtime.h>
#include <cmath>

#define L_     10
#define R_     64
#define G_     128
#define S_     256
#define MEL_   80
#define NCLS_  256
#define HOP_   64
#define END_   256
#define FRAMES_ 8
#define T_     512

typedef unsigned long long u64;

// ---- workspace layout (float offsets; mailboxes are u64, 8B-aligned) ----
#define COND8_OFF   0                                // 8*1280
#define HIST_OFF    10240                            // layers 1..8: [(j-1)][512][64]
#define MBX64_OFF   (HIST_OFF + 8*T_*R_)             // u64 x mailboxes [4][64]
#define CTR64_OFF   (MBX64_OFF + 4*R_*2)             // u64 contribs [10][256]
#define HID64_OFF   (CTR64_OFF + 10*S_*2)            // u64 C->D [256]
#define FLAG_OFF    (HID64_OFF + S_*2)               // flags, 16 ints apart

#define FID_PREV   11
#define FID_CLAIM  12

#define NROLE 7
#define SPIN_CAP (1 << 16)
#define LDS_SPIN_CAP (1 << 17)

// ====== tagged 64-bit mailbox protocol (r14-proven, XCD-0 pinned) ======
__device__ __forceinline__ void push_tag(u64* p, float v, int tag) {
  u64 pk = ((u64)(unsigned)tag << 32) | (unsigned)__float_as_int(v);
  asm volatile("global_atomic_swap_x2 %0, %1, off" :: "v"(p), "v"(pk) : "memory");
}
__device__ __forceinline__ float poll_tag(u64* p, int want) {
  u64 r; int n = 0;
  do {
    asm volatile("global_atomic_add_x2 %0, %1, %2, off sc0\n\ts_waitcnt vmcnt(0)"
                 : "=&v"(r) : "v"(p), "v"(0ULL) : "memory");
    if ((int)(r >> 32) >= want) break;
  } while (++n <= SPIN_CAP);
  return __int_as_float((int)(unsigned)(r & 0xffffffffULL));
}
__device__ __forceinline__ float2 poll_tag2(u64* p0, u64* p1, int want) {
  u64 r0, r1; int n = 0;
  for (;;) {
    asm volatile("global_atomic_add_x2 %0, %2, %4, off sc0\n\t"
                 "global_atomic_add_x2 %1, %3, %4, off sc0\n\t"
                 "s_waitcnt vmcnt(0)"
                 : "=&v"(r0), "=&v"(r1) : "v"(p0), "v"(p1), "v"(0ULL) : "memory");
    if ((int)(r0 >> 32) >= want && (int)(r1 >> 32) >= want) break;
    if (++n > SPIN_CAP) break;
  }
  return make_float2(__int_as_float((int)(unsigned)(r0 & 0xffffffffULL)),
                     __int_as_float((int)(unsigned)(r1 & 0xffffffffULL)));
}
__device__ __forceinline__ int flag_poll_atomic(int* p) {
  int v;
  asm volatile("global_atomic_add %0, %1, %2, off sc0\n\ts_waitcnt vmcnt(0)"
               : "=&v"(v) : "v"(p), "v"(0) : "memory");
  return v;
}
__device__ __forceinline__ void push_flag(int* p, int v) {
  asm volatile("global_atomic_swap %0, %1, off" :: "v"(p), "v"(v) : "memory");
}
__device__ __forceinline__ int wait_prev_wave(int* p, int want, int lane) {
  int v = 0, n = 0;
  do {
    if (lane == 0) v = flag_poll_atomic(p);
    v = __shfl(v, 0, 64);
    if ((v >> 16) >= want) break;
  } while (++n <= SPIN_CAP);
  return v & 0xffff;
}

// ---- LDS release/acquire sync (intra-CU; fences cover global+LDS) ----
__device__ __forceinline__ void lds_spin_ge(int* p, int want) {
  int n = 0;
  while (__hip_atomic_load(p, __ATOMIC_ACQUIRE, __HIP_MEMORY_SCOPE_WORKGROUP) < want) {
    if (++n > LDS_SPIN_CAP) break;
  }
}
__device__ __forceinline__ void lds_store_rel(int* p, int v) {
  __hip_atomic_store(p, v, __ATOMIC_RELEASE, __HIP_MEMORY_SCOPE_WORKGROUP);
}
__device__ __forceinline__ void lds_add_rel(int* p) {
  (void)__hip_atomic_fetch_add(p, 1, __ATOMIC_RELEASE, __HIP_MEMORY_SCOPE_WORKGROUP);
}

// ---- single-chain dot macros: EXACT r8/r14 arithmetic (absmax 0.0 proven).
// DO NOT restructure the fma chains or add orders (1-ulp knife edges).
#define DOTREG(N4, W, V4, ACC) do { \
  _Pragma("unroll") \
  for (int k_ = 0; k_ < (N4); ++k_) { float4 a_ = (V4)[k_]; \
    ACC = fmaf((W)[4*k_+0], a_.x, ACC); ACC = fmaf((W)[4*k_+1], a_.y, ACC); \
    ACC = fmaf((W)[4*k_+2], a_.z, ACC); ACC = fmaf((W)[4*k_+3], a_.w, ACC); } \
} while (0)

#define DOTREG_RELU(N4, W, V4, ACC) do { \
  _Pragma("unroll") \
  for (int k_ = 0; k_ < (N4); ++k_) { float4 a_ = (V4)[k_]; \
    a_.x = fmaxf(a_.x, 0.f); a_.y = fmaxf(a_.y, 0.f); \
    a_.z = fmaxf(a_.z, 0.f); a_.w = fmaxf(a_.w, 0.f); \
    ACC = fmaf((W)[4*k_+0], a_.x, ACC); ACC = fmaf((W)[4*k_+1], a_.y, ACC); \
    ACC = fmaf((W)[4*k_+2], a_.z, ACC); ACC = fmaf((W)[4*k_+3], a_.w, ACC); } \
} while (0)

__global__ void cond_prep_kernel(const float* __restrict__ condW,
                                 const float* __restrict__ y,
                                 float* __restrict__ cond8) {
  int idx = blockIdx.x * blockDim.x + threadIdx.x;
  if (idx >= FRAMES_ * L_ * G_) return;
  int f = idx / (L_ * G_);
  int row = idx - f * (L_ * G_);
  float acc = 0.f;
  for (int m = 0; m < MEL_; ++m)
    acc = fmaf(condW[row * MEL_ + m], y[m * FRAMES_ + f], acc);
  cond8[f * (L_ * G_) + row] = acc;
}

__global__ __launch_bounds__(256, 1) void wavenet_pipe(
    const float* __restrict__ samples,
    const int*   __restrict__ c_ptr,
    const float* __restrict__ emb,
    const float* __restrict__ WVp,
    const float* __restrict__ WVx,
    const float* __restrict__ Wo,
    const float* __restrict__ Wob,
    const float* __restrict__ Wol,
    const float* __restrict__ Wobl,
    const float* __restrict__ e1w,
    const float* __restrict__ e1b,
    const float* __restrict__ e2w,
    const float* __restrict__ e2b,
    float* __restrict__ ws,
    int*   __restrict__ out) {

  const int tid = threadIdx.x;

  float* cond8   = ws + COND8_OFF;
  float* hist    = ws + HIST_OFF;
  u64*   mbx     = (u64*)(ws + MBX64_OFF);
  u64*   contrib = (u64*)(ws + CTR64_OFF);
  u64*   mbhid   = (u64*)(ws + HID64_OFF);
  int*   flags   = (int*)(ws + FLAG_OFF);
  int*   fprev   = flags + FID_PREV * 16;

  __shared__ __align__(16) float x_s[R_];
  __shared__ __align__(16) float xb_s[R_];
  __shared__ __align__(16) float z_sa[R_];
  __shared__ __align__(16) float z_sb[R_];
  __shared__ __align__(16) float pd_sa[G_];
  __shared__ __align__(16) float pd_sb[G_];
  __shared__ __align__(16) float cond_a_s[FRAMES_ * G_];
  __shared__ __align__(16) float cond_b_s[FRAMES_ * G_];  // D reuses as logits
  __shared__ __align__(16) float biasC_s[10 * S_];        // C only
  __shared__ __align__(16) float vec_s[S_];
  __shared__ float wred[4], wsum[4];
  __shared__ int wcand[4];
  __shared__ int role_s;
  __shared__ int zctr, cdone;

  // ---- XCD-pinned role claiming (r7-proven) ----
  {
    unsigned xcc;
    asm volatile("s_getreg_b32 %0, hwreg(HW_REG_XCC_ID)" : "=s"(xcc));
    if (tid == 0) {
      int r = -1;
      if (xcc == 0) {
        int c0 = atomicAdd(flags + FID_CLAIM * 16, 1);
        if (c0 < NROLE) r = c0;
      }
      role_s = r;
      zctr = 0; cdone = 0;
    }
    __syncthreads();
  }
  const int bid = role_s;
  if (bid < 0) return;

  if (bid < 5) {
    // ====== B_k: layers j_a=2k, j_b=2k+1 — single-wave critical path ======
    const int k = bid;
    const int j_a = 2 * k, j_b = 2 * k + 1;
    const int dil_a = 1 << j_a, dil_b = 1 << j_b;

    float* hist_a = (k > 0) ? (hist + (size_t)(j_a - 1) * T_ * R_) : nullptr;
    float* hist_b = (k < 4) ? (hist + (size_t)(j_b - 1) * T_ * R_) : nullptr;
    u64* mbx_in    = mbx + (size_t)(k - 1) * R_;            // k>=1
    u64* mbx_out   = mbx + (size_t)k * R_;                  // k<4
    u64* contrib_a = contrib + (size_t)j_a * S_;
    u64* contrib_b = contrib + (size_t)j_b * S_;

    for (int i = tid; i < FRAMES_ * G_; i += 256) {
      cond_a_s[i] = cond8[(i >> 7) * (L_ * G_) + j_a * G_ + (i & 127)];
      cond_b_s[i] = cond8[(i >> 7) * (L_ * G_) + j_b * G_ + (i & 127)];
    }

    if (tid < 64) {
      // ------------- wave 0: the x critical path -------------
      const int r = tid;
      float gw_a[64], gf_a[64], gw_b[64], gf_b[64], wres_a[64], wres_b[64];
      float ba0 = 0.f, bb0 = 0.f;
      {
        const float4* p;
        p = (const float4*)(WVx + ((size_t)(j_a * G_ + r)) * R_);
        #pragma unroll
        for (int i = 0; i < 16; ++i) ((float4*)gw_a)[i] = p[i];
        p = (const float4*)(WVx + ((size_t)(j_a * G_ + r + 64)) * R_);
        #pragma unroll
        for (int i = 0; i < 16; ++i) ((float4*)gf_a)[i] = p[i];
        p = (const float4*)(WVx + ((size_t)(j_b * G_ + r)) * R_);
        #pragma unroll
        for (int i = 0; i < 16; ++i) ((float4*)gw_b)[i] = p[i];
        p = (const float4*)(WVx + ((size_t)(j_b * G_ + r + 64)) * R_);
        #pragma unroll
        for (int i = 0; i < 16; ++i) ((float4*)gf_b)[i] = p[i];
        p = (const float4*)(Wo + ((size_t)(j_a * (R_ + S_) + r)) * R_);
        #pragma unroll
        for (int i = 0; i < 16; ++i) ((float4*)wres_a)[i] = p[i];
        ba0 = Wob[j_a * (R_ + S_) + r];
        if (k < 4) {
          p = (const float4*)(Wo + ((size_t)(j_b * (R_ + S_) + r)) * R_);
          #pragma unroll
          for (int i = 0; i < 16; ++i) ((float4*)wres_b)[i] = p[i];
          bb0 = Wob[j_b * (R_ + S_) + r];
        } else {
          p = (const float4*)(Wol + (size_t)r * R_);   // contrib row r (bias at C)
          #pragma unroll
          for (int i = 0; i < 16; ++i) ((float4*)wres_b)[i] = p[i];
        }
      }
      __syncthreads();  // init done (pd_s initialized by waves 2-3)

      for (int t = 0; t < T_; ++t) {
        // back-pressure + pd(t) ready (waves finished step t-1)
        lds_spin_ge(&cdone, 3 * t);

        // acquire x
        float x;
        if (k == 0) {
          int prev = 127;
          if (t > 0) prev = wait_prev_wave(fprev, t, r);
          x = emb[(size_t)prev * R_ + r];
        } else {
          x = poll_tag(mbx_in + r, t + 1);
        }
        x_s[r] = x;

        // gate a + z_a (r14-exact: (c0+c1)+pd per row; both rows in-lane)
        {
          const float4* x4 = (const float4*)x_s;   // intra-wave: write->read safe
          float pdw = pd_sa[r], pdf = pd_sa[64 + r];
          float a0 = 0.f, a1 = 0.f, b0 = 0.f, b1 = 0.f;
          DOTREG(8, gw_a, x4, a0);       DOTREG(8, gw_a + 32, x4 + 8, a1);
          DOTREG(8, gf_a, x4, b0);       DOTREG(8, gf_a + 32, x4 + 8, b1);
          float hw = (a0 + a1) + pdw, hf = (b0 + b1) + pdf;
          z_sa[r] = tanhf(hw) * (1.f / (1.f + expf(-hf)));
        }
        if (r == 0) lds_store_rel(&zctr, 2 * t + 1);

        // residual a (r14-exact single 64-chain)
        float xb;
        {
          float v0 = 0.f;
          DOTREG(16, wres_a, (const float4*)z_sa, v0);
          xb = x + v0 + ba0;
          xb_s[r] = xb;
        }

        // gate b + z_b
        {
          const float4* x4 = (const float4*)xb_s;
          float pdw = pd_sb[r], pdf = pd_sb[64 + r];
          float a0 = 0.f, a1 = 0.f, b0 = 0.f, b1 = 0.f;
          DOTREG(8, gw_b, x4, a0);       DOTREG(8, gw_b + 32, x4 + 8, a1);
          DOTREG(8, gf_b, x4, b0);       DOTREG(8, gf_b + 32, x4 + 8, b1);
          float hw = (a0 + a1) + pdw, hf = (b0 + b1) + pdf;
          z_sb[r] = tanhf(hw) * (1.f / (1.f + expf(-hf)));
        }
        if (r == 0) lds_store_rel(&zctr, 2 * t + 2);

        // layer-b output: x push (k<4) or contrib rows 0..63 (k=4)
        {
          float v0 = 0.f;
          DOTREG(16, wres_b, (const float4*)z_sb, v0);
          if (k < 4) push_tag(mbx_out + r, xb + v0 + bb0, t + 1);
          else       push_tag(contrib_b + r, v0, t + 1);
        }
      }

    } else {
      // ------------- waves 1-3: contributions + hist + pd -------------
      const int u = tid - 64;           // 0..191
      float wca1[64], wca2[64], wcb1[64], wcb2[64];
      {
        const float4* p;
        p = (const float4*)(Wo + ((size_t)(j_a * (R_ + S_) + 64 + u)) * R_);
        #pragma unroll
        for (int i = 0; i < 16; ++i) ((float4*)wca1)[i] = p[i];
        if (u < 64) {
          p = (const float4*)(Wo + ((size_t)(j_a * (R_ + S_) + 256 + u)) * R_);
          #pragma unroll
          for (int i = 0; i < 16; ++i) ((float4*)wca2)[i] = p[i];
        }
        if (k < 4) {
          p = (const float4*)(Wo + ((size_t)(j_b * (R_ + S_) + 64 + u)) * R_);
          #pragma unroll
          for (int i = 0; i < 16; ++i) ((float4*)wcb1)[i] = p[i];
          if (u < 64) {
            p = (const float4*)(Wo + ((size_t)(j_b * (R_ + S_) + 256 + u)) * R_);
            #pragma unroll
            for (int i = 0; i < 16; ++i) ((float4*)wcb2)[i] = p[i];
          }
        } else {
          p = (const float4*)(Wol + (size_t)(64 + u) * R_);
          #pragma unroll
          for (int i = 0; i < 16; ++i) ((float4*)wcb1)[i] = p[i];
        }
      }
      // pd(t=0) init: rows pr = u-64 for u in [64,192)
      if (u >= 64) {
        const int pr = u - 64;
        pd_sa[pr] = cond_a_s[pr];
        pd_sb[pr] = cond_b_s[pr];
      }
      __syncthreads();

      for (int t = 0; t < T_; ++t) {
        // ---- layer-a contributions (z_a ready) ----
        lds_spin_ge(&zctr, 2 * t + 1);
        {
          float v = 0.f;
          DOTREG(16, wca1, (const float4*)z_sa, v);
          push_tag(contrib_a + u, v, t + 1);
          if (u < 64) {
            float v2 = 0.f;
            DOTREG(16, wca2, (const float4*)z_sa, v2);
            push_tag(contrib_a + 192 + u, v2, t + 1);
          }
        }
        if (k > 0 && u >= 176)
          ((float4*)(hist_a + (size_t)t * R_))[u - 176] = ((const float4*)x_s)[u - 176];

        // ---- layer-b contributions (z_b ready) ----
        lds_spin_ge(&zctr, 2 * t + 2);
        {
          float v = 0.f;
          DOTREG(16, wcb1, (const float4*)z_sb, v);
          push_tag(contrib_b + ((k < 4) ? u : (64 + u)), v, t + 1);
          if (k < 4 && u < 64) {
            float v2 = 0.f;
            DOTREG(16, wcb2, (const float4*)z_sb, v2);
            push_tag(contrib_b + 192 + u, v2, t + 1);
          }
        }
        if (k < 4 && u >= 160 && u < 176)
          ((float4*)(hist_b + (size_t)t * R_))[u - 160] = ((const float4*)xb_s)[u - 160];

        // ---- pd for t+1 (rows pr = u-64; r14-exact chains) ----
        const int tn = t + 1;
        if (tn < T_ && u >= 64) {
          const int pr = u - 64;
          const int f1 = tn >> 6;
          float wtmp[64];
          {
            const float4* wp4 = (const float4*)(WVp + ((size_t)(j_a * G_ + pr)) * R_);
            #pragma unroll
            for (int i = 0; i < 16; ++i) ((float4*)wtmp)[i] = wp4[i];
            float a0 = 0.f, a1 = 0.f;
            if (k == 0) {
              const float4* p4 = (const float4*)x_s;   // past(t+1) = x(t)
              DOTREG(8, wtmp, p4, a0);  DOTREG(8, wtmp + 32, p4 + 8, a1);
            } else {
              const int tp = tn - dil_a;
              if (tp >= 0) {
                const float4* p4 = (const float4*)(hist_a + (size_t)tp * R_);
                DOTREG(8, wtmp, p4, a0);  DOTREG(8, wtmp + 32, p4 + 8, a1);
              }
            }
            pd_sa[pr] = (a0 + a1) + cond_a_s[f1 * G_ + pr];
          }
          if (k < 4) {
            const float4* wp4 = (const float4*)(WVp + ((size_t)(j_b * G_ + pr)) * R_);
            #pragma unroll
            for (int i = 0; i < 16; ++i) ((float4*)wtmp)[i] = wp4[i];
            float a0 = 0.f, a1 = 0.f;
            const int tp = tn - dil_b;
            if (tp >= 0) {
              const float4* p4 = (const float4*)(hist_b + (size_t)tp * R_);
              DOTREG(8, wtmp, p4, a0);  DOTREG(8, wtmp + 32, p4 + 8, a1);
            }
            pd_sb[pr] = (a0 + a1) + cond_b_s[f1 * G_ + pr];
          } else {
            pd_sb[pr] = cond_b_s[f1 * G_ + pr];   // layer 9: past always 0 (dil=512)
          }
        }
        // step-t work done (release covers LDS pd writes + global hist writes)
        if ((u & 63) == 0) lds_add_rel(&cdone);
      }
    }

  } else if (bid == 5) {
    // ============ C: ordered skip fold + E1 (r14 verbatim) ============
    const int o_loc = tid >> 1, halfc = tid & 1;
    float w0[128], w1[128];
    {
      const float* p = e1w + ((size_t)o_loc) * S_ + halfc * 128;
      #pragma unroll
      for (int i = 0; i < 128; ++i) w0[i] = p[i];
      p = e1w + ((size_t)(128 + o_loc)) * S_ + halfc * 128;
      #pragma unroll
      for (int i = 0; i < 128; ++i) w1[i] = p[i];
    }
    const float bias0 = e1b[o_loc], bias1 = e1b[128 + o_loc];
    for (int i = tid; i < 10 * S_; i += 256) {
      int j = i >> 8, s = i & 255;
      biasC_s[i] = (j < 9) ? Wob[j * (R_ + S_) + 64 + s] : Wobl[s];
    }
    __syncthreads();

    for (int t = 0; t < T_; ++t) {
      float sacc = 0.f;
      for (int kk = 0; kk < 5; ++kk) {
        float2 v = poll_tag2(contrib + (size_t)(2 * kk) * S_ + tid,
                             contrib + (size_t)(2 * kk + 1) * S_ + tid, t + 1);
        sacc = (sacc + v.x) + biasC_s[(2 * kk) * S_ + tid];
        sacc = (sacc + v.y) + biasC_s[(2 * kk + 1) * S_ + tid];
      }
      vec_s[tid] = sacc;
      __syncthreads();
      const float4* s4 = (const float4*)(vec_s + halfc * 128);
      float v0 = 0.f, v1 = 0.f;
      DOTREG_RELU(32, w0, s4, v0);
      v0 += __shfl_down(v0, 1, 2);
      DOTREG_RELU(32, w1, s4, v1);
      v1 += __shfl_down(v1, 1, 2);
      if (halfc == 0) {
        push_tag(mbhid + o_loc,       fmaxf(v0 + bias0, 0.f), t + 1);
        push_tag(mbhid + 128 + o_loc, fmaxf(v1 + bias1, 0.f), t + 1);
      }
      __syncthreads();  // vec_s reuse guard
    }

  } else {
    // ============ D: E2 + sampling (r14 verbatim) ============
    const int o_loc = tid >> 1, halfc = tid & 1;
    const float cf = (float)c_ptr[0];
    float w0[128], w1[128];
    {
      const float* p = e2w + ((size_t)o_loc) * END_ + halfc * 128;
      #pragma unroll
      for (int i = 0; i < 128; ++i) w0[i] = p[i];
      p = e2w + ((size_t)(128 + o_loc)) * END_ + halfc * 128;
      #pragma unroll
      for (int i = 0; i < 128; ++i) w1[i] = p[i];
    }
    const float bias0 = e2b[o_loc], bias1 = e2b[128 + o_loc];
    float* logits_s = cond_b_s;  // reuse (unused by D)
    const int lane = tid & 63, wv = tid >> 6;

    for (int t = 0; t < T_; ++t) {
      vec_s[tid] = poll_tag(mbhid + tid, t + 1);
      __syncthreads();
      const float4* h4 = (const float4*)(vec_s + halfc * 128);
      float v0 = 0.f, v1 = 0.f;
      DOTREG(32, w0, h4, v0);
      v0 += __shfl_down(v0, 1, 2);
      DOTREG(32, w1, h4, v1);
      v1 += __shfl_down(v1, 1, 2);
      if (halfc == 0) {
        logits_s[o_loc]       = (v0 + bias0) * cf;
        logits_s[128 + o_loc] = (v1 + bias1) * cf;
      }
      __syncthreads();

      // ---- softmax-CDF sampling over 256 logits (r8 verbatim) ----
      float lg = logits_s[tid];
      float m = lg;
      #pragma unroll
      for (int off = 32; off >= 1; off >>= 1) m = fmaxf(m, __shfl_xor(m, off, 64));
      if (lane == 0) wred[wv] = m;
      __syncthreads();
      m = fmaxf(fmaxf(wred[0], wred[1]), fmaxf(wred[2], wred[3]));
      float e = expf(lg - m);
      float cs = e;
      #pragma unroll
      for (int off = 1; off < 64; off <<= 1) {
        float o_ = __shfl_up(cs, off, 64);
        if (lane >= off) cs += o_;
      }
      if (lane == 63) wsum[wv] = cs;
      __syncthreads();
      float total = wsum[0] + wsum[1] + wsum[2] + wsum[3];
      float offv = 0.f;
      for (int w2 = 0; w2 < wv; ++w2) offv += wsum[w2];
      float thresh = samples[t] * total;
      bool flagb = (offv + cs) > thresh;
      unsigned long long mk = __ballot(flagb);
      if (lane == 0) wcand[wv] = mk ? (wv * 64 + __ffsll(mk) - 1) : 100000;
      __syncthreads();
      if (tid == 0) {
        int nw = min(min(wcand[0], wcand[1]), min(wcand[2], wcand[3]));
        if (nw >= 100000) nw = 0;  // argmax of all-False -> 0
        out[t] = nw;
        push_flag(fprev, ((t + 1) << 16) | nw);
      }
      __syncthreads();  // protect wred/wsum/logits_s before next step
    }
  }
}

extern "C" void kernel_launch(void* const* d_in, const int* in_sizes, int n_in,
                              void* d_out, int out_size, void* d_ws, size_t ws_size,
                              hipStream_t stream) {
  const float* y       = (const float*)d_in[0];
  const float* samples = (const float*)d_in[1];
  const int*   c       = (const int*)d_in[2];
  const float* emb     = (const float*)d_in[3];
  const float* condW   = (const float*)d_in[4];
  const float* WVp     = (const float*)d_in[5];
  const float* WVx     = (const float*)d_in[6];
  const float* Wo      = (const float*)d_in[7];
  const float* Wob     = (const float*)d_in[8];
  const float* Wol     = (const float*)d_in[9];
  const float* Wobl    = (const float*)d_in[10];
  const float* e1w     = (const float*)d_in[11];
  const float* e1b     = (const float*)d_in[12];
  const float* e2w     = (const float*)d_in[13];
  const float* e2b     = (const float*)d_in[14];

  float* ws  = (float*)d_ws;
  int*   out = (int*)d_out;

  // Only flags need zeroing; mailbox tags rely on 0xAA poison reading as a
  // negative tag (never >= any t+1). Harness re-poisons ws every launch.
  hipMemsetAsync((char*)d_ws + (size_t)FLAG_OFF * sizeof(float), 0,
                 16 * 16 * sizeof(int), stream);

  cond_prep_kernel<<<(FRAMES_ * L_ * G_ + 255) / 256, 256, 0, stream>>>(
      condW, y, ws + COND8_OFF);

  wavenet_pipe<<<256, 256, 0, stream>>>(samples, c, emb, WVp, WVx, Wo, Wob,
                                        Wol, Wobl, e1w, e1b, e2w, e2b, ws, out);
}

// Round 16
// 9910.641 us; speedup vs baseline: 1.0399x; 1.0399x over previous
//
#include <hip/hip_runtime.h>
#include <cmath>

#define L_     10
#define R_     64
#define G_     128
#define S_     256
#define MEL_   80
#define NCLS_  256
#define HOP_   64
#define END_   256
#define FRAMES_ 8
#define T_     512

typedef unsigned long long u64;

// ---- workspace layout (float offsets; mailboxes are u64, 8B-aligned) ----
#define COND8_OFF   0                                // 8*1280
#define HIST_OFF    10240                            // layers 1..8: [(j-1)][512][64]
#define MBX64_OFF   (HIST_OFF + 8*T_*R_)             // u64 x mailboxes [4][64]
#define CTR64_OFF   (MBX64_OFF + 4*R_*2)             // u64 contribs [10][256]
#define HID64_OFF   (CTR64_OFF + 10*S_*2)            // u64 C->D [256]
#define FLAG_OFF    (HID64_OFF + S_*2)               // flags, 16 ints apart

#define FID_PREV   11
#define FID_CLAIM  12

#define NROLE 7
#define SPIN_CAP (1 << 16)
#define LDS_SPIN_CAP (1 << 17)

// ====== tagged 64-bit mailbox protocol (r14-proven, XCD-0 pinned) ======
__device__ __forceinline__ void push_tag(u64* p, float v, int tag) {
  u64 pk = ((u64)(unsigned)tag << 32) | (unsigned)__float_as_int(v);
  asm volatile("global_atomic_swap_x2 %0, %1, off" :: "v"(p), "v"(pk) : "memory");
}
__device__ __forceinline__ float poll_tag(u64* p, int want) {
  u64 r; int n = 0;
  do {
    asm volatile("global_atomic_add_x2 %0, %1, %2, off sc0\n\ts_waitcnt vmcnt(0)"
                 : "=&v"(r) : "v"(p), "v"(0ULL) : "memory");
    if ((int)(r >> 32) >= want) break;
  } while (++n <= SPIN_CAP);
  return __int_as_float((int)(unsigned)(r & 0xffffffffULL));
}
__device__ __forceinline__ float2 poll_tag2(u64* p0, u64* p1, int want) {
  u64 r0, r1; int n = 0;
  for (;;) {
    asm volatile("global_atomic_add_x2 %0, %2, %4, off sc0\n\t"
                 "global_atomic_add_x2 %1, %3, %4, off sc0\n\t"
                 "s_waitcnt vmcnt(0)"
                 : "=&v"(r0), "=&v"(r1) : "v"(p0), "v"(p1), "v"(0ULL) : "memory");
    if ((int)(r0 >> 32) >= want && (int)(r1 >> 32) >= want) break;
    if (++n > SPIN_CAP) break;
  }
  return make_float2(__int_as_float((int)(unsigned)(r0 & 0xffffffffULL)),
                     __int_as_float((int)(unsigned)(r1 & 0xffffffffULL)));
}
__device__ __forceinline__ int flag_poll_atomic(int* p) {
  int v;
  asm volatile("global_atomic_add %0, %1, %2, off sc0\n\ts_waitcnt vmcnt(0)"
               : "=&v"(v) : "v"(p), "v"(0) : "memory");
  return v;
}
__device__ __forceinline__ void push_flag(int* p, int v) {
  asm volatile("global_atomic_swap %0, %1, off" :: "v"(p), "v"(v) : "memory");
}
__device__ __forceinline__ int wait_prev_wave(int* p, int want, int lane) {
  int v = 0, n = 0;
  do {
    if (lane == 0) v = flag_poll_atomic(p);
    v = __shfl(v, 0, 64);
    if ((v >> 16) >= want) break;
  } while (++n <= SPIN_CAP);
  return v & 0xffff;
}

// ---- LDS release/acquire sync (r15-proven correct) ----
__device__ __forceinline__ void lds_spin_ge(int* p, int want) {
  int n = 0;
  while (__hip_atomic_load(p, __ATOMIC_ACQUIRE, __HIP_MEMORY_SCOPE_WORKGROUP) < want) {
    if (++n > LDS_SPIN_CAP) break;
  }
}
__device__ __forceinline__ void lds_store_rel(int* p, int v) {
  __hip_atomic_store(p, v, __ATOMIC_RELEASE, __HIP_MEMORY_SCOPE_WORKGROUP);
}
__device__ __forceinline__ void lds_add_rel(int* p) {
  (void)__hip_atomic_fetch_add(p, 1, __ATOMIC_RELEASE, __HIP_MEMORY_SCOPE_WORKGROUP);
}

// ---- single-chain dot macros: EXACT r14/r15 arithmetic (absmax 0.0 proven).
// DO NOT restructure the fma chains or add orders (1-ulp knife edges).
#define DOTREG(N4, W, V4, ACC) do { \
  _Pragma("unroll") \
  for (int k_ = 0; k_ < (N4); ++k_) { float4 a_ = (V4)[k_]; \
    ACC = fmaf((W)[4*k_+0], a_.x, ACC); ACC = fmaf((W)[4*k_+1], a_.y, ACC); \
    ACC = fmaf((W)[4*k_+2], a_.z, ACC); ACC = fmaf((W)[4*k_+3], a_.w, ACC); } \
} while (0)

#define DOTREG_RELU(N4, W, V4, ACC) do { \
  _Pragma("unroll") \
  for (int k_ = 0; k_ < (N4); ++k_) { float4 a_ = (V4)[k_]; \
    a_.x = fmaxf(a_.x, 0.f); a_.y = fmaxf(a_.y, 0.f); \
    a_.z = fmaxf(a_.z, 0.f); a_.w = fmaxf(a_.w, 0.f); \
    ACC = fmaf((W)[4*k_+0], a_.x, ACC); ACC = fmaf((W)[4*k_+1], a_.y, ACC); \
    ACC = fmaf((W)[4*k_+2], a_.z, ACC); ACC = fmaf((W)[4*k_+3], a_.w, ACC); } \
} while (0)

// streamed 64-dot, single chain (identical association to register version)
__device__ __forceinline__ float dot64_stream(const float* wrow, const float* v_s) {
  float w[64];
  const float4* p = (const float4*)wrow;
  #pragma unroll
  for (int i = 0; i < 16; ++i) ((float4*)w)[i] = p[i];
  float acc = 0.f;
  DOTREG(16, w, (const float4*)v_s, acc);
  return acc;
}
// streamed pd dot, dual chain (r15-exact)
__device__ __forceinline__ float pddot_stream(const float* wrow, const float* v_s) {
  float w[64];
  const float4* p = (const float4*)wrow;
  #pragma unroll
  for (int i = 0; i < 16; ++i) ((float4*)w)[i] = p[i];
  float a0 = 0.f, a1 = 0.f;
  DOTREG(8, w, (const float4*)v_s, a0);
  DOTREG(8, w + 32, ((const float4*)v_s) + 8, a1);
  return a0 + a1;
}

__global__ void cond_prep_kernel(const float* __restrict__ condW,
                                 const float* __restrict__ y,
                                 float* __restrict__ cond8) {
  int idx = blockIdx.x * blockDim.x + threadIdx.x;
  if (idx >= FRAMES_ * L_ * G_) return;
  int f = idx / (L_ * G_);
  int row = idx - f * (L_ * G_);
  float acc = 0.f;
  for (int m = 0; m < MEL_; ++m)
    acc = fmaf(condW[row * MEL_ + m], y[m * FRAMES_ + f], acc);
  cond8[f * (L_ * G_) + row] = acc;
}

__global__ __launch_bounds__(256, 1) void wavenet_pipe(
    const float* __restrict__ samples,
    const int*   __restrict__ c_ptr,
    const float* __restrict__ emb,
    const float* __restrict__ WVp,
    const float* __restrict__ WVx,
    const float* __restrict__ Wo,
    const float* __restrict__ Wob,
    const float* __restrict__ Wol,
    const float* __restrict__ Wobl,
    const float* __restrict__ e1w,
    const float* __restrict__ e1b,
    const float* __restrict__ e2w,
    const float* __restrict__ e2b,
    float* __restrict__ ws,
    int*   __restrict__ out) {

  const int tid = threadIdx.x;

  float* cond8   = ws + COND8_OFF;
  float* hist    = ws + HIST_OFF;
  u64*   mbx     = (u64*)(ws + MBX64_OFF);
  u64*   contrib = (u64*)(ws + CTR64_OFF);
  u64*   mbhid   = (u64*)(ws + HID64_OFF);
  int*   flags   = (int*)(ws + FLAG_OFF);
  int*   fprev   = flags + FID_PREV * 16;

  __shared__ __align__(16) float x_s[R_];
  __shared__ __align__(16) float xb_s[R_];
  __shared__ __align__(16) float z_sa[R_];
  __shared__ __align__(16) float z_sb[R_];
  __shared__ __align__(16) float pd_sa[G_];
  __shared__ __align__(16) float pd_sb[G_];
  __shared__ __align__(16) float cond_a_s[FRAMES_ * G_];
  __shared__ __align__(16) float cond_b_s[FRAMES_ * G_];  // D reuses as logits
  __shared__ __align__(16) float biasC_s[10 * S_];        // C only
  __shared__ __align__(16) float vec_s[S_];
  __shared__ float wred[4], wsum[4];
  __shared__ int wcand[4];
  __shared__ int role_s;
  __shared__ int zctr, cdone, xbflag;

  // ---- XCD-pinned role claiming (r7-proven) ----
  {
    unsigned xcc;
    asm volatile("s_getreg_b32 %0, hwreg(HW_REG_XCC_ID)" : "=s"(xcc));
    if (tid == 0) {
      int r = -1;
      if (xcc == 0) {
        int c0 = atomicAdd(flags + FID_CLAIM * 16, 1);
        if (c0 < NROLE) r = c0;
      }
      role_s = r;
      zctr = 0; cdone = 0; xbflag = 0;
    }
    __syncthreads();
  }
  const int bid = role_s;
  if (bid < 0) return;

  if (bid < 5) {
    // ====== B_k: layers j_a=2k, j_b=2k+1 ======
    // wave 0: layer a (192 weight floats, register-resident — NO spill)
    // wave 1: layer b (192 floats)
    // waves 2-3: all 512 contribution rows + 256 pd rows + hist, STREAMED
    const int k = bid;
    const int j_a = 2 * k, j_b = 2 * k + 1;
    const int dil_a = 1 << j_a, dil_b = 1 << j_b;

    float* hist_a = (k > 0) ? (hist + (size_t)(j_a - 1) * T_ * R_) : nullptr;
    float* hist_b = (k < 4) ? (hist + (size_t)(j_b - 1) * T_ * R_) : nullptr;
    u64* mbx_in    = mbx + (size_t)(k - 1) * R_;            // k>=1
    u64* mbx_out   = mbx + (size_t)k * R_;                  // k<4
    u64* contrib_a = contrib + (size_t)j_a * S_;
    u64* contrib_b = contrib + (size_t)j_b * S_;

    for (int i = tid; i < FRAMES_ * G_; i += 256) {
      cond_a_s[i] = cond8[(i >> 7) * (L_ * G_) + j_a * G_ + (i & 127)];
      cond_b_s[i] = cond8[(i >> 7) * (L_ * G_) + j_b * G_ + (i & 127)];
    }
    __syncthreads();  // cond ready for pd init

    if (tid < 64) {
      // ---------------- wave 0: layer a (x critical path) ----------------
      const int r = tid;
      float gw_a[64], gf_a[64], wres_a[64];
      float ba0;
      {
        const float4* p;
        p = (const float4*)(WVx + ((size_t)(j_a * G_ + r)) * R_);
        #pragma unroll
        for (int i = 0; i < 16; ++i) ((float4*)gw_a)[i] = p[i];
        p = (const float4*)(WVx + ((size_t)(j_a * G_ + r + 64)) * R_);
        #pragma unroll
        for (int i = 0; i < 16; ++i) ((float4*)gf_a)[i] = p[i];
        p = (const float4*)(Wo + ((size_t)(j_a * (R_ + S_) + r)) * R_);
        #pragma unroll
        for (int i = 0; i < 16; ++i) ((float4*)wres_a)[i] = p[i];
        ba0 = Wob[j_a * (R_ + S_) + r];
      }
      __syncthreads();  // init done

      for (int t = 0; t < T_; ++t) {
        lds_spin_ge(&cdone, 2 * t);   // pd(t) ready, buffers drained

        float x;
        if (k == 0) {
          int prev = 127;
          if (t > 0) prev = wait_prev_wave(fprev, t, r);
          x = emb[(size_t)prev * R_ + r];
        } else {
          x = poll_tag(mbx_in + r, t + 1);
        }
        x_s[r] = x;

        // gate a + z_a (r15-exact dual chains)
        {
          const float4* x4 = (const float4*)x_s;   // intra-wave write->read
          float pdw = pd_sa[r], pdf = pd_sa[64 + r];
          float a0 = 0.f, a1 = 0.f, b0 = 0.f, b1 = 0.f;
          DOTREG(8, gw_a, x4, a0);       DOTREG(8, gw_a + 32, x4 + 8, a1);
          DOTREG(8, gf_a, x4, b0);       DOTREG(8, gf_a + 32, x4 + 8, b1);
          float hw = (a0 + a1) + pdw, hf = (b0 + b1) + pdf;
          z_sa[r] = tanhf(hw) * (1.f / (1.f + expf(-hf)));
        }
        if (r == 0) lds_store_rel(&zctr, 2 * t + 1);

        // residual a (r14-exact single chain)
        {
          float v0 = 0.f;
          DOTREG(16, wres_a, (const float4*)z_sa, v0);
          xb_s[r] = x + v0 + ba0;
        }
        if (r == 0) lds_store_rel(&xbflag, t + 1);
      }

    } else if (tid < 128) {
      // ---------------- wave 1: layer b (x critical path) ----------------
      const int r = tid - 64;
      float gw_b[64], gf_b[64], wres_b[64];
      float bb0 = 0.f;
      {
        const float4* p;
        p = (const float4*)(WVx + ((size_t)(j_b * G_ + r)) * R_);
        #pragma unroll
        for (int i = 0; i < 16; ++i) ((float4*)gw_b)[i] = p[i];
        p = (const float4*)(WVx + ((size_t)(j_b * G_ + r + 64)) * R_);
        #pragma unroll
        for (int i = 0; i < 16; ++i) ((float4*)gf_b)[i] = p[i];
        if (k < 4) {
          p = (const float4*)(Wo + ((size_t)(j_b * (R_ + S_) + r)) * R_);
          #pragma unroll
          for (int i = 0; i < 16; ++i) ((float4*)wres_b)[i] = p[i];
          bb0 = Wob[j_b * (R_ + S_) + r];
        } else {
          p = (const float4*)(Wol + (size_t)r * R_);   // contrib row r (bias at C)
          #pragma unroll
          for (int i = 0; i < 16; ++i) ((float4*)wres_b)[i] = p[i];
        }
      }
      __syncthreads();  // init done

      for (int t = 0; t < T_; ++t) {
        lds_spin_ge(&xbflag, t + 1);   // xb(t) ready (covers x_s/z_sa/xb_s)
        float xb = xb_s[r];

        // gate b + z_b (r15-exact dual chains)
        {
          const float4* x4 = (const float4*)xb_s;
          float pdw = pd_sb[r], pdf = pd_sb[64 + r];
          float a0 = 0.f, a1 = 0.f, b0 = 0.f, b1 = 0.f;
          DOTREG(8, gw_b, x4, a0);       DOTREG(8, gw_b + 32, x4 + 8, a1);
          DOTREG(8, gf_b, x4, b0);       DOTREG(8, gf_b + 32, x4 + 8, b1);
          float hw = (a0 + a1) + pdw, hf = (b0 + b1) + pdf;
          z_sb[r] = tanhf(hw) * (1.f / (1.f + expf(-hf)));
        }
        if (r == 0) lds_store_rel(&zctr, 2 * t + 2);

        // layer-b output (r14-exact single chain) + push
        {
          float v0 = 0.f;
          DOTREG(16, wres_b, (const float4*)z_sb, v0);
          if (k < 4) push_tag(mbx_out + r, xb + v0 + bb0, t + 1);
          else       push_tag(contrib_b + r, v0, t + 1);
        }
      }

    } else {
      // -------- waves 2-3: streamed contributions + pd + hist --------
      const int u = tid - 128;   // 0..127
      // pd init (cond ready after the pre-split barrier)
      pd_sa[u] = cond_a_s[u];
      pd_sb[u] = cond_b_s[u];
      __syncthreads();  // init done

      for (int t = 0; t < T_; ++t) {
        // ---- layer-a contributions (z_a ready); slot s = Wo row 64+s ----
        lds_spin_ge(&zctr, 2 * t + 1);
        {
          float v = dot64_stream(Wo + ((size_t)(j_a * (R_ + S_) + 64 + u)) * R_, z_sa);
          push_tag(contrib_a + u, v, t + 1);
          float v2 = dot64_stream(Wo + ((size_t)(j_a * (R_ + S_) + 192 + u)) * R_, z_sa);
          push_tag(contrib_a + 128 + u, v2, t + 1);
        }
        if (k > 0 && u >= 112)
          ((float4*)(hist_a + (size_t)t * R_))[u - 112] = ((const float4*)x_s)[u - 112];

        // ---- layer-b contributions (z_b ready) ----
        lds_spin_ge(&zctr, 2 * t + 2);
        if (k < 4) {
          float v = dot64_stream(Wo + ((size_t)(j_b * (R_ + S_) + 64 + u)) * R_, z_sb);
          push_tag(contrib_b + u, v, t + 1);
          float v2 = dot64_stream(Wo + ((size_t)(j_b * (R_ + S_) + 192 + u)) * R_, z_sb);
          push_tag(contrib_b + 128 + u, v2, t + 1);
        } else {
          // layer 9: slots 64..255 = Wol rows 64..255 (slots 0..63 by wave 1)
          float v = dot64_stream(Wol + (size_t)(64 + u) * R_, z_sb);
          push_tag(contrib_b + 64 + u, v, t + 1);
          if (u < 64) {
            float v2 = dot64_stream(Wol + (size_t)(192 + u) * R_, z_sb);
            push_tag(contrib_b + 192 + u, v2, t + 1);
          }
        }
        if (k < 4 && u >= 96 && u < 112)
          ((float4*)(hist_b + (size_t)t * R_))[u - 96] = ((const float4*)xb_s)[u - 96];

        // ---- pd for t+1 (row u; r15-exact chains, streamed weights) ----
        const int tn = t + 1;
        if (tn < T_) {
          const int f1 = tn >> 6;
          {
            float s = 0.f;
            if (k == 0) {
              s = pddot_stream(WVp + ((size_t)(j_a * G_ + u)) * R_, x_s);  // past=x(t)
            } else {
              const int tp = tn - dil_a;
              if (tp >= 0)
                s = pddot_stream(WVp + ((size_t)(j_a * G_ + u)) * R_,
                                 hist_a + (size_t)tp * R_);
            }
            pd_sa[u] = s + cond_a_s[f1 * G_ + u];
          }
          if (k < 4) {
            float s = 0.f;
            const int tp = tn - dil_b;
            if (tp >= 0)
              s = pddot_stream(WVp + ((size_t)(j_b * G_ + u)) * R_,
                               hist_b + (size_t)tp * R_);
            pd_sb[u] = s + cond_b_s[f1 * G_ + u];
          } else {
            pd_sb[u] = cond_b_s[f1 * G_ + u];   // layer 9: past always 0
          }
        }
        if ((u & 63) == 0) lds_add_rel(&cdone);   // 2 increments per step
      }
    }

  } else if (bid == 5) {
    // ============ C: ordered skip fold + E1 (r14 verbatim) ============
    const int o_loc = tid >> 1, halfc = tid & 1;
    float w0[128], w1[128];
    {
      const float* p = e1w + ((size_t)o_loc) * S_ + halfc * 128;
      #pragma unroll
      for (int i = 0; i < 128; ++i) w0[i] = p[i];
      p = e1w + ((size_t)(128 + o_loc)) * S_ + halfc * 128;
      #pragma unroll
      for (int i = 0; i < 128; ++i) w1[i] = p[i];
    }
    const float bias0 = e1b[o_loc], bias1 = e1b[128 + o_loc];
    for (int i = tid; i < 10 * S_; i += 256) {
      int j = i >> 8, s = i & 255;
      biasC_s[i] = (j < 9) ? Wob[j * (R_ + S_) + 64 + s] : Wobl[s];
    }
    __syncthreads();

    for (int t = 0; t < T_; ++t) {
      float sacc = 0.f;
      for (int kk = 0; kk < 5; ++kk) {
        float2 v = poll_tag2(contrib + (size_t)(2 * kk) * S_ + tid,
                             contrib + (size_t)(2 * kk + 1) * S_ + tid, t + 1);
        sacc = (sacc + v.x) + biasC_s[(2 * kk) * S_ + tid];
        sacc = (sacc + v.y) + biasC_s[(2 * kk + 1) * S_ + tid];
      }
      vec_s[tid] = sacc;
      __syncthreads();
      const float4* s4 = (const float4*)(vec_s + halfc * 128);
      float v0 = 0.f, v1 = 0.f;
      DOTREG_RELU(32, w0, s4, v0);
      v0 += __shfl_down(v0, 1, 2);
      DOTREG_RELU(32, w1, s4, v1);
      v1 += __shfl_down(v1, 1, 2);
      if (halfc == 0) {
        push_tag(mbhid + o_loc,       fmaxf(v0 + bias0, 0.f), t + 1);
        push_tag(mbhid + 128 + o_loc, fmaxf(v1 + bias1, 0.f), t + 1);
      }
      __syncthreads();  // vec_s reuse guard
    }

  } else {
    // ============ D: E2 + sampling (r14 verbatim) ============
    const int o_loc = tid >> 1, halfc = tid & 1;
    const float cf = (float)c_ptr[0];
    float w0[128], w1[128];
    {
      const float* p = e2w + ((size_t)o_loc) * END_ + halfc * 128;
      #pragma unroll
      for (int i = 0; i < 128; ++i) w0[i] = p[i];
      p = e2w + ((size_t)(128 + o_loc)) * END_ + halfc * 128;
      #pragma unroll
      for (int i = 0; i < 128; ++i) w1[i] = p[i];
    }
    const float bias0 = e2b[o_loc], bias1 = e2b[128 + o_loc];
    float* logits_s = cond_b_s;  // reuse (unused by D)
    const int lane = tid & 63, wv = tid >> 6;

    for (int t = 0; t < T_; ++t) {
      vec_s[tid] = poll_tag(mbhid + tid, t + 1);
      __syncthreads();
      const float4* h4 = (const float4*)(vec_s + halfc * 128);
      float v0 = 0.f, v1 = 0.f;
      DOTREG(32, w0, h4, v0);
      v0 += __shfl_down(v0, 1, 2);
      DOTREG(32, w1, h4, v1);
      v1 += __shfl_down(v1, 1, 2);
      if (halfc == 0) {
        logits_s[o_loc]       = (v0 + bias0) * cf;
        logits_s[128 + o_loc] = (v1 + bias1) * cf;
      }
      __syncthreads();

      // ---- softmax-CDF sampling over 256 logits (r8 verbatim) ----
      float lg = logits_s[tid];
      float m = lg;
      #pragma unroll
      for (int off = 32; off >= 1; off >>= 1) m = fmaxf(m, __shfl_xor(m, off, 64));
      if (lane == 0) wred[wv] = m;
      __syncthreads();
      m = fmaxf(fmaxf(wred[0], wred[1]), fmaxf(wred[2], wred[3]));
      float e = expf(lg - m);
      float cs = e;
      #pragma unroll
      for (int off = 1; off < 64; off <<= 1) {
        float o_ = __shfl_up(cs, off, 64);
        if (lane >= off) cs += o_;
      }
      if (lane == 63) wsum[wv] = cs;
      __syncthreads();
      float total = wsum[0] + wsum[1] + wsum[2] + wsum[3];
      float offv = 0.f;
      for (int w2 = 0; w2 < wv; ++w2) offv += wsum[w2];
      float thresh = samples[t] * total;
      bool flagb = (offv + cs) > thresh;
      unsigned long long mk = __ballot(flagb);
      if (lane == 0) wcand[wv] = mk ? (wv * 64 + __ffsll(mk) - 1) : 100000;
      __syncthreads();
      if (tid == 0) {
        int nw = min(min(wcand[0], wcand[1]), min(wcand[2], wcand[3]));
        if (nw >= 100000) nw = 0;  // argmax of all-False -> 0
        out[t] = nw;
        push_flag(fprev, ((t + 1) << 16) | nw);
      }
      __syncthreads();  // protect wred/wsum/logits_s before next step
    }
  }
}

extern "C" void kernel_launch(void* const* d_in, const int* in_sizes, int n_in,
                              void* d_out, int out_size, void* d_ws, size_t ws_size,
                              hipStream_t stream) {
  const float* y       = (const float*)d_in[0];
  const float* samples = (const float*)d_in[1];
  const int*   c       = (const int*)d_in[2];
  const float* emb     = (const float*)d_in[3];
  const float* condW   = (const float*)d_in[4];
  const float* WVp     = (const float*)d_in[5];
  const float* WVx     = (const float*)d_in[6];
  const float* Wo      = (const float*)d_in[7];
  const float* Wob     = (const float*)d_in[8];
  const float* Wol     = (const float*)d_in[9];
  const float* Wobl    = (const float*)d_in[10];
  const float* e1w     = (const float*)d_in[11];
  const float* e1b     = (const float*)d_in[12];
  const float* e2w     = (const float*)d_in[13];
  const float* e2b     = (const float*)d_in[14];

  float* ws  = (float*)d_ws;
  int*   out = (int*)d_out;

  // Only flags need zeroing; mailbox tags rely on 0xAA poison reading as a
  // negative tag (never >= any t+1). Harness re-poisons ws every launch.
  hipMemsetAsync((char*)d_ws + (size_t)FLAG_OFF * sizeof(float), 0,
                 16 * 16 * sizeof(int), stream);

  cond_prep_kernel<<<(FRAMES_ * L_ * G_ + 255) / 256, 256, 0, stream>>>(
      condW, y, ws + COND8_OFF);

  wavenet_pipe<<<256, 256, 0, stream>>>(samples, c, emb, WVp, WVx, Wo, Wob,
                                        Wol, Wobl, e1w, e1b, e2w, e2b, ws, out);
}